// Round 24
// baseline (209.146 us; speedup 1.0000x reference)
//
#include <hip/hip_runtime.h>
#include <hip/hip_bf16.h>

// ---------------------------------------------------------------------------
// CausalSelfAttention: y = proj( softmax_causal( (xWqkv+b).q @ k^T / 8 ) @ v )
// B=4, T=2048, C=1024, H=16, D=64.  bf16 MFMA compute, fp32 accumulate.
// ---------------------------------------------------------------------------

typedef __attribute__((ext_vector_type(8)))  __bf16 bf16x8;
typedef __attribute__((ext_vector_type(2)))  float  f32x2;
typedef __attribute__((ext_vector_type(4)))  float  f32x4;
typedef __attribute__((ext_vector_type(16))) float  f32x16;
typedef __attribute__((ext_vector_type(4)))  unsigned int u32x4;

#define AS1C(p) ((const __attribute__((address_space(1))) unsigned int*)(p))
#define AS3(p)  ((__attribute__((address_space(3))) unsigned int*)(p))

__device__ __forceinline__ unsigned short f2bfu(float f){
  __hip_bfloat16 h = __float2bfloat16(f);
  return __builtin_bit_cast(unsigned short, h);
}

// v_permlane32_swap_b32: a.hi(lanes32-63) <-> b.lo(lanes0-31), both modified.
// ONLY safe when a and b hold distinct values (distinct vregs).
__device__ __forceinline__ void plswapu(unsigned int &a, unsigned int &b){
  asm("v_permlane32_swap_b32 %0, %1" : "+v"(a), "+v"(b));
}
// pack two f32 -> one u32 of 2 bf16 (lo = first arg)
__device__ __forceinline__ unsigned int cvtpk(float lo, float hi){
  unsigned int r;
  asm("v_cvt_pk_bf16_f32 %0, %1, %2" : "=v"(r) : "v"(lo), "v"(hi));
  return r;
}
__device__ __forceinline__ float max3f(float a, float b, float c){
  float r;
  asm("v_max3_f32 %0, %1, %2, %3" : "=v"(r) : "v"(a), "v"(b), "v"(c));
  return r;
}

// ---------------- merged prologue: x->bf16 + both weight transposes ---------

__global__ __launch_bounds__(256)
void prep_all(const float* __restrict__ x, __hip_bfloat16* __restrict__ xb,
              const float* __restrict__ w_attn, __hip_bfloat16* __restrict__ wattnT,
              const float* __restrict__ w_proj, __hip_bfloat16* __restrict__ wprojT)
{
  __shared__ float tile[32][33];
  const int idx = blockIdx.x;
  if (idx < 2048){
    const int n4 = 8388608/4;
    for (int i = idx*256 + threadIdx.x; i < n4; i += 2048*256){
      float4 v = reinterpret_cast<const float4*>(x)[i];
      ushort4 u;
      u.x = f2bfu(v.x); u.y = f2bfu(v.y); u.z = f2bfu(v.z); u.w = f2bfu(v.w);
      reinterpret_cast<ushort4*>(xb)[i] = u;
    }
  } else {
    const float* in; __hip_bfloat16* out; int C, R, bx, by;
    if (idx < 5120){
      const int f = idx - 2048;
      in = w_attn; out = wattnT; R = 1024; C = 3072;
      bx = f % 96; by = f / 96;
    } else {
      const int f = idx - 5120;
      in = w_proj; out = wprojT; R = 1024; C = 1024;
      bx = f & 31; by = f >> 5;
    }
    const int tx = threadIdx.x & 31, ty = threadIdx.x >> 5;
    const int c0 = bx*32, r0 = by*32;
    for (int i = ty; i < 32; i += 8)
      tile[i][tx] = in[(size_t)(r0+i)*C + c0 + tx];
    __syncthreads();
    for (int i = ty; i < 32; i += 8)
      out[(size_t)(c0+i)*R + r0 + tx] = __float2bfloat16(tile[tx][i]);
  }
}

// ---------------- bf16 GEMM (128x128, BK=32, dbuf-2 + T2 + grouped raster) --
// R18/R22-exact: GM=4, T2 swizzle (conflicts 0), ring-2.

#define QSCALE 0.1803368801111244f   // 0.125 * log2(e) -> softmax in exp2 space

__device__ __forceinline__ void stage_ab(const __hip_bfloat16* __restrict__ A,
                                         const __hip_bfloat16* __restrict__ Bt,
                                         int m0, int n0, int K, int kt,
                                         __hip_bfloat16* sA, __hip_bfloat16* sB,
                                         int w, int l)
{
  const int k0 = kt*32;
  #pragma unroll
  for (int qq = 0; qq < 2; ++qq){
    const int c = qq*256 + w*64 + l;        // 16B chunk id, 512 per tile
    const int row = c>>2, kc = c&3;         // 4 chunks per 32-elem row
    const int kcs = kc ^ ((row>>1)&3);      // T2 pre-swizzled source chunk
    __builtin_amdgcn_global_load_lds(AS1C(A  + (size_t)(m0+row)*K + k0 + 8*kcs),
                                     AS3(sA + (qq*256 + w*64)*8), 16, 0, 0);
    __builtin_amdgcn_global_load_lds(AS1C(Bt + (size_t)(n0+row)*K + k0 + 8*kcs),
                                     AS3(sB + (qq*256 + w*64)*8), 16, 0, 0);
  }
}

template<int EPI>
__global__ __launch_bounds__(256)
void gemm_bf16(const __hip_bfloat16* __restrict__ A,
               const __hip_bfloat16* __restrict__ Bt,
               const float* __restrict__ bias,
               int M, int N, int K,
               __hip_bfloat16* __restrict__ q_s,
               __hip_bfloat16* __restrict__ k_s,
               __hip_bfloat16* __restrict__ vT_s,
               float* __restrict__ outf)
{
  __shared__ __align__(16) __hip_bfloat16 sA[2][128*32];
  __shared__ __align__(16) __hip_bfloat16 sB[2][128*32];
  const int tid = threadIdx.x, w = tid>>6, l = tid&63, g = l>>4, li = l&15;
  const int wm = w>>1, wn = w&1;
  const int sw = (li>>1)&3;                 // T2 read-side swizzle (per-lane)

  const int nwg = gridDim.x, cpx = nwg >> 3;
  const int swz = (blockIdx.x & 7)*cpx + (blockIdx.x >> 3);
  const int nbx = N >> 7;
  const int GM = 4, chunk = GM * nbx;
  const int grp = swz / chunk, pos = swz - grp*chunk;
  const int m0 = (grp*GM + (pos & (GM-1)))*128;
  const int n0 = (pos >> 2)*128;            // pos / GM  (GM == 4)

  f32x4 acc[4][4] = {};

  const int NT = K >> 5;
  stage_ab(A, Bt, m0, n0, K, 0, sA[0], sB[0], w, l);
  int cur = 0;

  for (int kt = 0; kt < NT; ++kt){
    __syncthreads();                       // buf[cur] staged (vmcnt drained)
    if (kt + 1 < NT)
      stage_ab(A, Bt, m0, n0, K, kt+1, sA[cur^1], sB[cur^1], w, l);

    bf16x8 af[4], bfr[4];
    #pragma unroll
    for (int mi = 0; mi < 4; ++mi)
      af[mi] = *reinterpret_cast<const bf16x8*>(sA[cur] + (wm*64 + mi*16 + li)*32 + 8*(g ^ sw));
    #pragma unroll
    for (int ni = 0; ni < 4; ++ni)
      bfr[ni] = *reinterpret_cast<const bf16x8*>(sB[cur] + (wn*64 + ni*16 + li)*32 + 8*(g ^ sw));
    #pragma unroll
    for (int mi = 0; mi < 4; ++mi)
      #pragma unroll
      for (int ni = 0; ni < 4; ++ni)
        acc[mi][ni] = __builtin_amdgcn_mfma_f32_16x16x32_bf16(af[mi], bfr[ni], acc[mi][ni], 0, 0, 0);
    cur ^= 1;
  }

  #pragma unroll
  for (int ni = 0; ni < 4; ++ni){
    const int col = n0 + wn*64 + ni*16 + li;
    const float bv = bias[col];
    #pragma unroll
    for (int mi = 0; mi < 4; ++mi){
      #pragma unroll
      for (int e = 0; e < 4; ++e){
        const int row = m0 + wm*64 + mi*16 + 4*g + e;
        const float val = acc[mi][ni][e] + bv;
        if (EPI == 0){
          const int three = col >> 10, h = (col >> 6) & 15, d = col & 63;
          const int b = row >> 11, t = row & 2047;
          const int bh = b*16 + h;
          if (three == 0)      q_s[((size_t)bh*2048 + t)*64 + d]  = __float2bfloat16(val*QSCALE);
          else if (three == 1) k_s[((size_t)bh*2048 + t)*64 + d]  = __float2bfloat16(val);
          else                 vT_s[((size_t)bh*64 + d)*2048 + t] = __float2bfloat16(val);  // V^T
        } else {
          outf[(size_t)row*N + col] = val;
        }
      }
    }
  }
}

// ---------------- flash attention (quad blocks + deferred-PV pipeline) ------
// Block = 256 thr (4 waves); wave w owns 32-row q-tile (4v + w); diagonals
// {2v,2v,2v+1,2v+1}; ALL waves share one staged KV stream 0..2v+1 (waves 0/1
// idle only on the final tile, ~3% waste).  LDS = sk ring-2 + svt ring-3 =
// 40 KB serving 4 waves -> 4 blocks/CU = 16 waves/CU (4/SIMD; R23 had 2).
// Deferred-PV pipeline: iter j issues QK(j) + PV(j-1) back-to-back, then
// softmax(j) -> pfr.  Trip count 2v+2 uniform per block (no barrier
// divergence) and even (clean pfrA/pfrB pairing).  Waves 0/1 finish PV(jd)
// in-loop at j=jmax (svP = V(jd)); waves 2/3 finish in epilogue (pfrB).
// Per-CU balance: residue-class permutation (classes sum to 30 -> uniform
// 68 rounds/CU).  bh pinned to XCD (bid&7).  Defer-max; setprio.

__device__ __forceinline__ void stage_kv64(const __hip_bfloat16* __restrict__ k_s,
                                           const __hip_bfloat16* __restrict__ vT_s,
                                           size_t base, int j,
                                           __hip_bfloat16* sk, __hip_bfloat16* svt,
                                           int tid)
{
  #pragma unroll
  for (int it = 0; it < 2; ++it){
    const int c = it*256 + tid;            // 512 chunks of 16B per 8KB tile
    const int r = c>>3, cc = c&7;          // 8 chunks per 128B row
    __builtin_amdgcn_global_load_lds(AS1C(k_s  + base + (size_t)(j*64 + r)*64 + 8*(cc ^ (r&7))),
                                     AS3(sk  + c*8), 16, 0, 0);
    __builtin_amdgcn_global_load_lds(AS1C(vT_s + base + (size_t)r*2048 + j*64 + 8*(cc ^ (r&7))),
                                     AS3(svt + c*8), 16, 0, 0);
  }
}

__device__ __forceinline__ bf16x8 ldtile(const __hip_bfloat16* t, int row, int chunk){
  return *reinterpret_cast<const bf16x8*>(t + row*64 + ((chunk ^ (row&7))*8));
}

__global__ __launch_bounds__(256, 3)
void flash_attn(const __hip_bfloat16* __restrict__ q_s,
                const __hip_bfloat16* __restrict__ k_s,
                const __hip_bfloat16* __restrict__ vT_s,
                __hip_bfloat16* __restrict__ y_s)
{
  __shared__ __align__(16) __hip_bfloat16 sk [2][64*64];
  __shared__ __align__(16) __hip_bfloat16 svt[3][64*64];

  const int tid = threadIdx.x, w = tid>>6, l = tid&63;
  const int lq = l&31, hf = l>>5, h4 = 4*hf;
  const int bid = blockIdx.x;
  const int xcd = bid & 7, sl = (bid>>3) & 7;
  const int q = bid >> 6;                    // quad slot 0..15
  // residue-class balanced permutation (classes {q,q+4,q+8,q+12} sum to 30)
  const int v = (q < 4 || q >= 12) ? (15 - q) : ((q < 8) ? q + 4 : q - 4);
  const int bh = xcd*8 + sl;                 // bh pinned to XCD bh>>3
  const size_t base = (size_t)bh * (2048*64);
  const int b = bh >> 4, hh = bh & 15;

  const int tw = 4*v + w;                    // this wave's 32-row q-tile
  const int jd = 2*v + (w >> 1);             // wave's diagonal kv tile
  const int jmax = 2*v + 1;                  // block's staged range (odd)
  const int qabs = 32*tw + lq;
  const int rel = 32*(w & 1) + lq;           // diagonal-tile causal bound

  bf16x8 qf[4];
  #pragma unroll
  for (int ks = 0; ks < 4; ++ks)
    qf[ks] = *reinterpret_cast<const bf16x8*>(q_s + base + (size_t)qabs*64 + 16*ks + 8*hf);

  f32x16 o0 = {}, o1 = {};
  float mrun = -1e30f, lrun = 0.f;
  bf16x8 pfrA[4], pfrB[4];

  __hip_bfloat16 *skC = sk[0],  *skN = sk[1];
  __hip_bfloat16 *svP = svt[2], *svC = svt[0], *svN = svt[1];

  stage_kv64(k_s, vT_s, base, 0, skC, svC, tid);

  // STEP: barrier; stage(j+1); QK(j)[j<=jd] + PV(j-1, PFR_C)[0<=j-1<=jd];
  // softmax(j)[j<=jd] -> PFR_P; rotate rings.
  #define ATTN_STEP(J, PFR_P, PFR_C)                                          \
  {                                                                           \
    const int j_ = (J);                                                       \
    __syncthreads();                                                          \
    if (j_ + 1 <= jmax)                                                       \
      stage_kv64(k_s, vT_s, base, j_+1, skN, svN, tid);                       \
    f32x16 s0 = {}, s1 = {};                                                  \
    __builtin_amdgcn_s_setprio(1);                                            \
    if (j_ <= jd){                                                            \
      _Pragma("unroll")                                                       \
      for (int ks = 0; ks < 4; ++ks){                                         \
        bf16x8 kf0 = ldtile(skC, lq,      2*ks + hf);                         \
        s0 = __builtin_amdgcn_mfma_f32_32x32x16_bf16(kf0, qf[ks], s0, 0,0,0); \
        bf16x8 kf1 = ldtile(skC, 32 + lq, 2*ks + hf);                         \
        s1 = __builtin_amdgcn_mfma_f32_32x32x16_bf16(kf1, qf[ks], s1, 0,0,0); \
      }                                                                       \
    }                                                                         \
    if (j_ > 0 && j_ - 1 <= jd){                                              \
      _Pragma("unroll")                                                       \
      for (int ks = 0; ks < 4; ++ks){                                         \
        bf16x8 vf0 = ldtile(svP, lq,      2*ks + hf);                         \
        o0 = __builtin_amdgcn_mfma_f32_32x32x16_bf16(vf0, PFR_C[ks], o0,0,0,0);\
        bf16x8 vf1 = ldtile(svP, 32 + lq, 2*ks + hf);                         \
        o1 = __builtin_amdgcn_mfma_f32_32x32x16_bf16(vf1, PFR_C[ks], o1,0,0,0);\
      }                                                                       \
    }                                                                         \
    __builtin_amdgcn_s_setprio(0);                                            \
    if (j_ <= jd){                                                            \
      f32x2 pf2[16];                                                          \
      _Pragma("unroll")                                                       \
      for (int i = 0; i < 8; ++i){                                            \
        pf2[i]     = (f32x2){ s0[2*i], s0[2*i+1] };                           \
        pf2[8 + i] = (f32x2){ s1[2*i], s1[2*i+1] };                           \
      }                                                                       \
      if (j_ == jd){                                                          \
        _Pragma("unroll")                                                     \
        for (int i = 0; i < 16; ++i){                                         \
          const int a = i >> 3;                                               \
          const int r0i = (i & 7)*2, r1i = r0i + 1;                           \
          const int kv0 = 32*a + (r0i&3) + 8*(r0i>>2) + h4;                   \
          const int kv1 = 32*a + (r1i&3) + 8*(r1i>>2) + h4;                   \
          pf2[i].x = (kv0 <= rel) ? pf2[i].x : -1e30f;                        \
          pf2[i].y = (kv1 <= rel) ? pf2[i].y : -1e30f;                        \
        }                                                                     \
      }                                                                       \
      float t0 = max3f(PFX(0),PFX(1),PFX(2)),   t1 = max3f(PFX(3),PFX(4),PFX(5));   \
      float t2 = max3f(PFX(6),PFX(7),PFX(8)),   t3 = max3f(PFX(9),PFX(10),PFX(11)); \
      float t4 = max3f(PFX(12),PFX(13),PFX(14)),t5 = max3f(PFX(15),PFX(16),PFX(17));\
      float t6 = max3f(PFX(18),PFX(19),PFX(20)),t7 = max3f(PFX(21),PFX(22),PFX(23));\
      float t8 = max3f(PFX(24),PFX(25),PFX(26)),t9 = max3f(PFX(27),PFX(28),PFX(29));\
      float t10 = fmaxf(PFX(30),PFX(31));                                     \
      float u0 = max3f(t0,t1,t2), u1 = max3f(t3,t4,t5), u2 = max3f(t6,t7,t8); \
      float u3 = fmaxf(t9,t10);                                               \
      float pm = fmaxf(max3f(u0,u1,u2), u3);                                  \
      if (!__all(pm - mrun <= 8.0f)){                                         \
        pm = fmaxf(pm, __shfl_xor(pm, 32));                                   \
        const float nm = fmaxf(mrun, pm);                                     \
        const float corr = exp2f(mrun - nm);                                  \
        mrun = nm;                                                            \
        o0 *= corr; o1 *= corr;                                               \
        lrun *= corr;                                                         \
      }                                                                       \
      const f32x2 negm = { -mrun, -mrun };                                    \
      _Pragma("unroll")                                                       \
      for (int i = 0; i < 16; ++i) pf2[i] = pf2[i] + negm;                    \
      _Pragma("unroll")                                                       \
      for (int i = 0; i < 16; ++i){                                           \
        pf2[i].x = exp2f(pf2[i].x);                                           \
        pf2[i].y = exp2f(pf2[i].y);                                           \
      }                                                                       \
      f32x2 q8[8];                                                            \
      _Pragma("unroll")                                                       \
      for (int i = 0; i < 8; ++i) q8[i] = pf2[i] + pf2[8+i];                  \
      f32x2 q4a = q8[0]+q8[4], q4b = q8[1]+q8[5], q4c = q8[2]+q8[6], q4d = q8[3]+q8[7];\
      f32x2 q2a = q4a+q4c, q2b = q4b+q4d;                                     \
      f32x2 q1 = q2a+q2b;                                                     \
      float psum = q1.x + q1.y;                                               \
      psum += __shfl_xor(psum, 32);                                           \
      lrun += psum;                                                           \
      unsigned int wds[16];                                                   \
      _Pragma("unroll")                                                       \
      for (int k = 0; k < 16; ++k) wds[k] = cvtpk(pf2[k].x, pf2[k].y);        \
      _Pragma("unroll")                                                       \
      for (int a = 0; a < 2; ++a)                                             \
        _Pragma("unroll")                                                     \
        for (int bl = 0; bl < 2; ++bl){                                       \
          plswapu(wds[a*8 + 4*bl    ], wds[a*8 + 4*bl + 2]);                  \
          plswapu(wds[a*8 + 4*bl + 1], wds[a*8 + 4*bl + 3]);                  \
        }                                                                     \
      _Pragma("unroll")                                                       \
      for (int B = 0; B < 4; ++B){                                            \
        u32x4 tt = { wds[4*B], wds[4*B+1], wds[4*B+2], wds[4*B+3] };          \
        PFR_P[B] = __builtin_bit_cast(bf16x8, tt);                            \
      }                                                                       \
    }                                                                         \
    /* rotate rings: skC<->skN; {svP,svC,svN} <- {svC,svN,svP} */             \
    { __hip_bfloat16* t_ = skC; skC = skN; skN = t_; }                        \
    { __hip_bfloat16* t_ = svP; svP = svC; svC = svN; svN = t_; }             \
  }

  #define PFX(K) (((K)&1) ? pf2[(K)>>1].y : pf2[(K)>>1].x)
  #pragma unroll 1
  for (int j = 0; j + 1 <= jmax; j += 2){    // trip count jmax+1 always even
    ATTN_STEP(j,   pfrA, pfrB);
    ATTN_STEP(j+1, pfrB, pfrA);
  }
  #undef PFX
  #undef ATTN_STEP

  // epilogue PV for waves with jd == jmax (w >= 2): pfr(jd) is pfrB (jd odd),
  // svP = V(jmax) after the final rotation.
  if (jd == jmax){
    #pragma unroll
    for (int ks = 0; ks < 4; ++ks){
      bf16x8 vf0 = ldtile(svP, lq,      2*ks + hf);
      o0 = __builtin_amdgcn_mfma_f32_32x32x16_bf16(vf0, pfrB[ks], o0, 0, 0, 0);
      bf16x8 vf1 = ldtile(svP, 32 + lq, 2*ks + hf);
      o1 = __builtin_amdgcn_mfma_f32_32x32x16_bf16(vf1, pfrB[ks], o1, 0, 0, 0);
    }
  }

  // ---- epilogue: y[b*2048 + q][hh*64 + d] ----
  const float inv = 1.f / lrun;
  __hip_bfloat16* yp = y_s + ((size_t)(b*2048 + qabs))*1024 + hh*64;
  #pragma unroll
  for (int i = 0; i < 8; ++i){
    const int d = (2*i & 3) + 8*(i>>1) + h4;     // r=2i -> (r&3)+8*(r>>2)+4h
    *reinterpret_cast<unsigned int*>(yp + d)      = cvtpk(o0[2*i]*inv, o0[2*i+1]*inv);
    *reinterpret_cast<unsigned int*>(yp + 32 + d) = cvtpk(o1[2*i]*inv, o1[2*i+1]*inv);
  }
}

// ---------------- launch ----------------

extern "C" void kernel_launch(void* const* d_in, const int* in_sizes, int n_in,
                              void* d_out, int out_size, void* d_ws, size_t ws_size,
                              hipStream_t stream)
{
  const float* x      = (const float*)d_in[0];
  const float* w_attn = (const float*)d_in[1];
  const float* b_attn = (const float*)d_in[2];
  const float* w_proj = (const float*)d_in[3];
  const float* b_proj = (const float*)d_in[4];
  float* out = (float*)d_out;
  char* ws = (char*)d_ws;

  __hip_bfloat16* xb     = (__hip_bfloat16*)(ws + 0);          // 16 MB [8192][1024]
  __hip_bfloat16* wattnT = (__hip_bfloat16*)(ws + 16777216);   //  6 MB [3072][1024]
  __hip_bfloat16* wprojT = (__hip_bfloat16*)(ws + 23068672);   //  2 MB [1024][1024]
  __hip_bfloat16* q_s    = (__hip_bfloat16*)(ws + 25165824);   // 16 MB [64bh][2048][64]
  __hip_bfloat16* k_s    = (__hip_bfloat16*)(ws + 41943040);   // 16 MB [64bh][2048][64]
  __hip_bfloat16* vT_s   = (__hip_bfloat16*)(ws + 58720256);   // 16 MB [64bh][64][2048]
  __hip_bfloat16* y_s    = xb;                                  // reuse xb after gemm1

  prep_all<<<6144, 256, 0, stream>>>(x, xb, w_attn, wattnT, w_proj, wprojT);

  gemm_bf16<0><<<1536, 256, 0, stream>>>(
      xb, wattnT, b_attn, 8192, 3072, 1024, q_s, k_s, vT_s, (float*)nullptr);

  flash_attn<<<1024, 256, 0, stream>>>(q_s, k_s, vT_s, y_s);

  gemm_bf16<1><<<512, 256, 0, stream>>>(
      y_s, wprojT, b_proj, 8192, 1024, 1024,
      (__hip_bfloat16*)nullptr, (__hip_bfloat16*)nullptr, (__hip_bfloat16*)nullptr, out);
}

// Round 25
// 186.723 us; speedup vs baseline: 1.1201x; 1.1201x over previous
//
#include <hip/hip_runtime.h>
#include <hip/hip_bf16.h>

// ---------------------------------------------------------------------------
// CausalSelfAttention: y = proj( softmax_causal( (xWqkv+b).q @ k^T / 8 ) @ v )
// B=4, T=2048, C=1024, H=16, D=64.  bf16 MFMA compute, fp32 accumulate.
// R23-exact configuration (best measured: 186.7 us).
// ---------------------------------------------------------------------------

typedef __attribute__((ext_vector_type(8)))  __bf16 bf16x8;
typedef __attribute__((ext_vector_type(2)))  float  f32x2;
typedef __attribute__((ext_vector_type(4)))  float  f32x4;
typedef __attribute__((ext_vector_type(16))) float  f32x16;
typedef __attribute__((ext_vector_type(4)))  unsigned int u32x4;

#define AS1C(p) ((const __attribute__((address_space(1))) unsigned int*)(p))
#define AS3(p)  ((__attribute__((address_space(3))) unsigned int*)(p))

__device__ __forceinline__ unsigned short f2bfu(float f){
  __hip_bfloat16 h = __float2bfloat16(f);
  return __builtin_bit_cast(unsigned short, h);
}

// v_permlane32_swap_b32: a.hi(lanes32-63) <-> b.lo(lanes0-31), both modified.
// ONLY safe when a and b hold distinct values (distinct vregs).
__device__ __forceinline__ void plswapu(unsigned int &a, unsigned int &b){
  asm("v_permlane32_swap_b32 %0, %1" : "+v"(a), "+v"(b));
}
// pack two f32 -> one u32 of 2 bf16 (lo = first arg)
__device__ __forceinline__ unsigned int cvtpk(float lo, float hi){
  unsigned int r;
  asm("v_cvt_pk_bf16_f32 %0, %1, %2" : "=v"(r) : "v"(lo), "v"(hi));
  return r;
}
__device__ __forceinline__ float max3f(float a, float b, float c){
  float r;
  asm("v_max3_f32 %0, %1, %2, %3" : "=v"(r) : "v"(a), "v"(b), "v"(c));
  return r;
}

// ---------------- merged prologue: x->bf16 + both weight transposes ---------

__global__ __launch_bounds__(256)
void prep_all(const float* __restrict__ x, __hip_bfloat16* __restrict__ xb,
              const float* __restrict__ w_attn, __hip_bfloat16* __restrict__ wattnT,
              const float* __restrict__ w_proj, __hip_bfloat16* __restrict__ wprojT)
{
  __shared__ float tile[32][33];
  const int idx = blockIdx.x;
  if (idx < 2048){
    const int n4 = 8388608/4;
    for (int i = idx*256 + threadIdx.x; i < n4; i += 2048*256){
      float4 v = reinterpret_cast<const float4*>(x)[i];
      ushort4 u;
      u.x = f2bfu(v.x); u.y = f2bfu(v.y); u.z = f2bfu(v.z); u.w = f2bfu(v.w);
      reinterpret_cast<ushort4*>(xb)[i] = u;
    }
  } else {
    const float* in; __hip_bfloat16* out; int C, R, bx, by;
    if (idx < 5120){
      const int f = idx - 2048;
      in = w_attn; out = wattnT; R = 1024; C = 3072;
      bx = f % 96; by = f / 96;
    } else {
      const int f = idx - 5120;
      in = w_proj; out = wprojT; R = 1024; C = 1024;
      bx = f & 31; by = f >> 5;
    }
    const int tx = threadIdx.x & 31, ty = threadIdx.x >> 5;
    const int c0 = bx*32, r0 = by*32;
    for (int i = ty; i < 32; i += 8)
      tile[i][tx] = in[(size_t)(r0+i)*C + c0 + tx];
    __syncthreads();
    for (int i = ty; i < 32; i += 8)
      out[(size_t)(c0+i)*R + r0 + tx] = __float2bfloat16(tile[tx][i]);
  }
}

// ---------------- bf16 GEMM (128x128, BK=32, dbuf-2 + T2 + grouped raster) --
// R18/R22-exact: GM=4, T2 swizzle (conflicts 0), ring-2.

#define QSCALE 0.1803368801111244f   // 0.125 * log2(e) -> softmax in exp2 space

__device__ __forceinline__ void stage_ab(const __hip_bfloat16* __restrict__ A,
                                         const __hip_bfloat16* __restrict__ Bt,
                                         int m0, int n0, int K, int kt,
                                         __hip_bfloat16* sA, __hip_bfloat16* sB,
                                         int w, int l)
{
  const int k0 = kt*32;
  #pragma unroll
  for (int qq = 0; qq < 2; ++qq){
    const int c = qq*256 + w*64 + l;        // 16B chunk id, 512 per tile
    const int row = c>>2, kc = c&3;         // 4 chunks per 32-elem row
    const int kcs = kc ^ ((row>>1)&3);      // T2 pre-swizzled source chunk
    __builtin_amdgcn_global_load_lds(AS1C(A  + (size_t)(m0+row)*K + k0 + 8*kcs),
                                     AS3(sA + (qq*256 + w*64)*8), 16, 0, 0);
    __builtin_amdgcn_global_load_lds(AS1C(Bt + (size_t)(n0+row)*K + k0 + 8*kcs),
                                     AS3(sB + (qq*256 + w*64)*8), 16, 0, 0);
  }
}

template<int EPI>
__global__ __launch_bounds__(256)
void gemm_bf16(const __hip_bfloat16* __restrict__ A,
               const __hip_bfloat16* __restrict__ Bt,
               const float* __restrict__ bias,
               int M, int N, int K,
               __hip_bfloat16* __restrict__ q_s,
               __hip_bfloat16* __restrict__ k_s,
               __hip_bfloat16* __restrict__ vT_s,
               float* __restrict__ outf)
{
  __shared__ __align__(16) __hip_bfloat16 sA[2][128*32];
  __shared__ __align__(16) __hip_bfloat16 sB[2][128*32];
  const int tid = threadIdx.x, w = tid>>6, l = tid&63, g = l>>4, li = l&15;
  const int wm = w>>1, wn = w&1;
  const int sw = (li>>1)&3;                 // T2 read-side swizzle (per-lane)

  const int nwg = gridDim.x, cpx = nwg >> 3;
  const int swz = (blockIdx.x & 7)*cpx + (blockIdx.x >> 3);
  const int nbx = N >> 7;
  const int GM = 4, chunk = GM * nbx;
  const int grp = swz / chunk, pos = swz - grp*chunk;
  const int m0 = (grp*GM + (pos & (GM-1)))*128;
  const int n0 = (pos >> 2)*128;            // pos / GM  (GM == 4)

  f32x4 acc[4][4] = {};

  const int NT = K >> 5;
  stage_ab(A, Bt, m0, n0, K, 0, sA[0], sB[0], w, l);
  int cur = 0;

  for (int kt = 0; kt < NT; ++kt){
    __syncthreads();                       // buf[cur] staged (vmcnt drained)
    if (kt + 1 < NT)
      stage_ab(A, Bt, m0, n0, K, kt+1, sA[cur^1], sB[cur^1], w, l);

    bf16x8 af[4], bfr[4];
    #pragma unroll
    for (int mi = 0; mi < 4; ++mi)
      af[mi] = *reinterpret_cast<const bf16x8*>(sA[cur] + (wm*64 + mi*16 + li)*32 + 8*(g ^ sw));
    #pragma unroll
    for (int ni = 0; ni < 4; ++ni)
      bfr[ni] = *reinterpret_cast<const bf16x8*>(sB[cur] + (wn*64 + ni*16 + li)*32 + 8*(g ^ sw));
    #pragma unroll
    for (int mi = 0; mi < 4; ++mi)
      #pragma unroll
      for (int ni = 0; ni < 4; ++ni)
        acc[mi][ni] = __builtin_amdgcn_mfma_f32_16x16x32_bf16(af[mi], bfr[ni], acc[mi][ni], 0, 0, 0);
    cur ^= 1;
  }

  #pragma unroll
  for (int ni = 0; ni < 4; ++ni){
    const int col = n0 + wn*64 + ni*16 + li;
    const float bv = bias[col];
    #pragma unroll
    for (int mi = 0; mi < 4; ++mi){
      #pragma unroll
      for (int e = 0; e < 4; ++e){
        const int row = m0 + wm*64 + mi*16 + 4*g + e;
        const float val = acc[mi][ni][e] + bv;
        if (EPI == 0){
          const int three = col >> 10, h = (col >> 6) & 15, d = col & 63;
          const int b = row >> 11, t = row & 2047;
          const int bh = b*16 + h;
          if (three == 0)      q_s[((size_t)bh*2048 + t)*64 + d]  = __float2bfloat16(val*QSCALE);
          else if (three == 1) k_s[((size_t)bh*2048 + t)*64 + d]  = __float2bfloat16(val);
          else                 vT_s[((size_t)bh*64 + d)*2048 + t] = __float2bfloat16(val);  // V^T
        } else {
          outf[(size_t)row*N + col] = val;
        }
      }
    }
  }
}

// ---------------- flash attention (duo blocks + deferred-PV pipeline) -------
// R18 duo structure (2 waves, same diagonal jd=v, shared KV stream, LPT,
// XCD-pinned bh) with software pipeline: iteration j issues QK(j) AND
// PV(j-1) back-to-back (independent MFMAs), THEN softmax(j) -> pfr.
// PV no longer waits behind softmax; softmax's stall on s0 overlaps PV.
// Defer-max rescale at j is correct: PV(j-1) already accumulated into o.
// sk ring-2 + svt ring-3 = 40 KB LDS (4 blocks/CU).  pfrA/pfrB static names
// (rule #20); final PV(jd) in a parity-selected epilogue.

__device__ __forceinline__ void stage_kv64(const __hip_bfloat16* __restrict__ k_s,
                                           const __hip_bfloat16* __restrict__ vT_s,
                                           size_t base, int j,
                                           __hip_bfloat16* sk, __hip_bfloat16* svt,
                                           int tid)
{
  #pragma unroll
  for (int it = 0; it < 4; ++it){
    const int c = it*128 + tid;            // 512 chunks of 16B per 8KB tile
    const int r = c>>3, cc = c&7;          // 8 chunks per 128B row
    __builtin_amdgcn_global_load_lds(AS1C(k_s  + base + (size_t)(j*64 + r)*64 + 8*(cc ^ (r&7))),
                                     AS3(sk  + c*8), 16, 0, 0);
    __builtin_amdgcn_global_load_lds(AS1C(vT_s + base + (size_t)r*2048 + j*64 + 8*(cc ^ (r&7))),
                                     AS3(svt + c*8), 16, 0, 0);
  }
}

__device__ __forceinline__ bf16x8 ldtile(const __hip_bfloat16* t, int row, int chunk){
  return *reinterpret_cast<const bf16x8*>(t + row*64 + ((chunk ^ (row&7))*8));
}

__global__ __launch_bounds__(128, 2)
void flash_attn(const __hip_bfloat16* __restrict__ q_s,
                const __hip_bfloat16* __restrict__ k_s,
                const __hip_bfloat16* __restrict__ vT_s,
                __hip_bfloat16* __restrict__ y_s)
{
  __shared__ __align__(16) __hip_bfloat16 sk [2][64*64];
  __shared__ __align__(16) __hip_bfloat16 svt[3][64*64];

  const int tid = threadIdx.x, w = tid>>6, l = tid&63;
  const int lq = l&31, hf = l>>5, h4 = 4*hf;
  const int bid = blockIdx.x;
  const int xcd = bid & 7, sl = (bid>>3) & 7;
  const int v = 31 - (bid >> 6);             // duo index, biggest first (LPT)
  const int bh = xcd*8 + sl;                 // bh pinned to XCD bh>>3
  const size_t base = (size_t)bh * (2048*64);
  const int b = bh >> 4, hh = bh & 15;

  const int tw = 2*v + w;                    // this wave's 32-row q-tile
  const int jd = v;                          // SAME diagonal for both waves
  const int qabs = 32*tw + lq;
  const int rel = 32*w + lq;                 // diagonal-tile causal bound

  bf16x8 qf[4];
  #pragma unroll
  for (int ks = 0; ks < 4; ++ks)
    qf[ks] = *reinterpret_cast<const bf16x8*>(q_s + base + (size_t)qabs*64 + 16*ks + 8*hf);

  f32x16 o0 = {}, o1 = {};
  float mrun = -1e30f, lrun = 0.f;
  bf16x8 pfrA[4], pfrB[4];

  __hip_bfloat16 *skC = sk[0],  *skN = sk[1];
  __hip_bfloat16 *svP = svt[2], *svC = svt[0], *svN = svt[1];

  stage_kv64(k_s, vT_s, base, 0, skC, svC, tid);

  // STEP: barrier; stage(j+1); QK(j) + PV(j-1, PFR_C); softmax(j) -> PFR_P;
  // rotate rings.
  #define ATTN_STEP(J, PFR_P, PFR_C)                                          \
  {                                                                           \
    const int j_ = (J);                                                       \
    __syncthreads();                                                          \
    if (j_ + 1 <= jd)                                                         \
      stage_kv64(k_s, vT_s, base, j_+1, skN, svN, tid);                       \
    f32x16 s0 = {}, s1 = {};                                                  \
    __builtin_amdgcn_s_setprio(1);                                            \
    _Pragma("unroll")                                                         \
    for (int ks = 0; ks < 4; ++ks){                                           \
      bf16x8 kf0 = ldtile(skC, lq,      2*ks + hf);                           \
      s0 = __builtin_amdgcn_mfma_f32_32x32x16_bf16(kf0, qf[ks], s0, 0,0,0);   \
      bf16x8 kf1 = ldtile(skC, 32 + lq, 2*ks + hf);                           \
      s1 = __builtin_amdgcn_mfma_f32_32x32x16_bf16(kf1, qf[ks], s1, 0,0,0);   \
    }                                                                         \
    if (j_ > 0){                                                              \
      _Pragma("unroll")                                                       \
      for (int ks = 0; ks < 4; ++ks){                                         \
        bf16x8 vf0 = ldtile(svP, lq,      2*ks + hf);                         \
        o0 = __builtin_amdgcn_mfma_f32_32x32x16_bf16(vf0, PFR_C[ks], o0,0,0,0);\
        bf16x8 vf1 = ldtile(svP, 32 + lq, 2*ks + hf);                         \
        o1 = __builtin_amdgcn_mfma_f32_32x32x16_bf16(vf1, PFR_C[ks], o1,0,0,0);\
      }                                                                       \
    }                                                                         \
    __builtin_amdgcn_s_setprio(0);                                            \
    /* packed in-register softmax (lane owns q-row qabs) */                   \
    f32x2 pf2[16];                                                            \
    _Pragma("unroll")                                                         \
    for (int i = 0; i < 8; ++i){                                              \
      pf2[i]     = (f32x2){ s0[2*i], s0[2*i+1] };                             \
      pf2[8 + i] = (f32x2){ s1[2*i], s1[2*i+1] };                             \
    }                                                                         \
    if (j_ == jd){                                                            \
      _Pragma("unroll")                                                       \
      for (int i = 0; i < 16; ++i){                                           \
        const int a = i >> 3;                                                 \
        const int r0i = (i & 7)*2, r1i = r0i + 1;                             \
        const int kv0 = 32*a + (r0i&3) + 8*(r0i>>2) + h4;                     \
        const int kv1 = 32*a + (r1i&3) + 8*(r1i>>2) + h4;                     \
        pf2[i].x = (kv0 <= rel) ? pf2[i].x : -1e30f;                          \
        pf2[i].y = (kv1 <= rel) ? pf2[i].y : -1e30f;                          \
      }                                                                       \
    }                                                                         \
    float t0 = max3f(PFX(0),PFX(1),PFX(2)),   t1 = max3f(PFX(3),PFX(4),PFX(5));   \
    float t2 = max3f(PFX(6),PFX(7),PFX(8)),   t3 = max3f(PFX(9),PFX(10),PFX(11)); \
    float t4 = max3f(PFX(12),PFX(13),PFX(14)),t5 = max3f(PFX(15),PFX(16),PFX(17));\
    float t6 = max3f(PFX(18),PFX(19),PFX(20)),t7 = max3f(PFX(21),PFX(22),PFX(23));\
    float t8 = max3f(PFX(24),PFX(25),PFX(26)),t9 = max3f(PFX(27),PFX(28),PFX(29));\
    float t10 = fmaxf(PFX(30),PFX(31));                                       \
    float u0 = max3f(t0,t1,t2), u1 = max3f(t3,t4,t5), u2 = max3f(t6,t7,t8);   \
    float u3 = fmaxf(t9,t10);                                                 \
    float pm = fmaxf(max3f(u0,u1,u2), u3);                                    \
    if (!__all(pm - mrun <= 8.0f)){                                           \
      pm = fmaxf(pm, __shfl_xor(pm, 32));                                     \
      const float nm = fmaxf(mrun, pm);                                       \
      const float corr = exp2f(mrun - nm);                                    \
      mrun = nm;                                                              \
      o0 *= corr; o1 *= corr;                                                 \
      lrun *= corr;                                                           \
    }                                                                         \
    const f32x2 negm = { -mrun, -mrun };                                      \
    _Pragma("unroll")                                                         \
    for (int i = 0; i < 16; ++i) pf2[i] = pf2[i] + negm;                      \
    _Pragma("unroll")                                                         \
    for (int i = 0; i < 16; ++i){                                             \
      pf2[i].x = exp2f(pf2[i].x);                                             \
      pf2[i].y = exp2f(pf2[i].y);                                             \
    }                                                                         \
    f32x2 q8[8];                                                              \
    _Pragma("unroll")                                                         \
    for (int i = 0; i < 8; ++i) q8[i] = pf2[i] + pf2[8+i];                    \
    f32x2 q4a = q8[0]+q8[4], q4b = q8[1]+q8[5], q4c = q8[2]+q8[6], q4d = q8[3]+q8[7];\
    f32x2 q2a = q4a+q4c, q2b = q4b+q4d;                                       \
    f32x2 q1 = q2a+q2b;                                                       \
    float psum = q1.x + q1.y;                                                 \
    psum += __shfl_xor(psum, 32);                                             \
    lrun += psum;                                                             \
    unsigned int wds[16];                                                     \
    _Pragma("unroll")                                                         \
    for (int k = 0; k < 16; ++k) wds[k] = cvtpk(pf2[k].x, pf2[k].y);          \
    _Pragma("unroll")                                                         \
    for (int a = 0; a < 2; ++a)                                               \
      _Pragma("unroll")                                                       \
      for (int bl = 0; bl < 2; ++bl){                                         \
        plswapu(wds[a*8 + 4*bl    ], wds[a*8 + 4*bl + 2]);                    \
        plswapu(wds[a*8 + 4*bl + 1], wds[a*8 + 4*bl + 3]);                    \
      }                                                                       \
    _Pragma("unroll")                                                         \
    for (int B = 0; B < 4; ++B){                                              \
      u32x4 tt = { wds[4*B], wds[4*B+1], wds[4*B+2], wds[4*B+3] };            \
      PFR_P[B] = __builtin_bit_cast(bf16x8, tt);                              \
    }                                                                         \
    /* rotate rings: skC<->skN; {svP,svC,svN} <- {svC,svN,svP} */             \
    { __hip_bfloat16* t_ = skC; skC = skN; skN = t_; }                        \
    { __hip_bfloat16* t_ = svP; svP = svC; svC = svN; svN = t_; }             \
  }

  #define PFX(K) (((K)&1) ? pf2[(K)>>1].y : pf2[(K)>>1].x)
  int j = 0;
  #pragma unroll 1
  for (; j + 1 <= jd; j += 2){
    ATTN_STEP(j,   pfrA, pfrB);
    ATTN_STEP(j+1, pfrB, pfrA);
  }
  if (j <= jd)
    ATTN_STEP(j, pfrA, pfrB);
  #undef PFX
  #undef ATTN_STEP

  // final PV(jd): last produced pfr is pfrA if jd even, pfrB if jd odd.
  // after the last rotation, svP points at tile jd's buffer.
  if ((jd & 1) == 0){
    #pragma unroll
    for (int ks = 0; ks < 4; ++ks){
      bf16x8 vf0 = ldtile(svP, lq,      2*ks + hf);
      o0 = __builtin_amdgcn_mfma_f32_32x32x16_bf16(vf0, pfrA[ks], o0, 0, 0, 0);
      bf16x8 vf1 = ldtile(svP, 32 + lq, 2*ks + hf);
      o1 = __builtin_amdgcn_mfma_f32_32x32x16_bf16(vf1, pfrA[ks], o1, 0, 0, 0);
    }
  } else {
    #pragma unroll
    for (int ks = 0; ks < 4; ++ks){
      bf16x8 vf0 = ldtile(svP, lq,      2*ks + hf);
      o0 = __builtin_amdgcn_mfma_f32_32x32x16_bf16(vf0, pfrB[ks], o0, 0, 0, 0);
      bf16x8 vf1 = ldtile(svP, 32 + lq, 2*ks + hf);
      o1 = __builtin_amdgcn_mfma_f32_32x32x16_bf16(vf1, pfrB[ks], o1, 0, 0, 0);
    }
  }

  // ---- epilogue: y[b*2048 + q][hh*64 + d] ----
  const float inv = 1.f / lrun;
  __hip_bfloat16* yp = y_s + ((size_t)(b*2048 + qabs))*1024 + hh*64;
  #pragma unroll
  for (int i = 0; i < 8; ++i){
    const int d = (2*i & 3) + 8*(i>>1) + h4;     // r=2i -> (r&3)+8*(r>>2)+4h
    *reinterpret_cast<unsigned int*>(yp + d)      = cvtpk(o0[2*i]*inv, o0[2*i+1]*inv);
    *reinterpret_cast<unsigned int*>(yp + 32 + d) = cvtpk(o1[2*i]*inv, o1[2*i+1]*inv);
  }
}

// ---------------- launch ----------------

extern "C" void kernel_launch(void* const* d_in, const int* in_sizes, int n_in,
                              void* d_out, int out_size, void* d_ws, size_t ws_size,
                              hipStream_t stream)
{
  const float* x      = (const float*)d_in[0];
  const float* w_attn = (const float*)d_in[1];
  const float* b_attn = (const float*)d_in[2];
  const float* w_proj = (const float*)d_in[3];
  const float* b_proj = (const float*)d_in[4];
  float* out = (float*)d_out;
  char* ws = (char*)d_ws;

  __hip_bfloat16* xb     = (__hip_bfloat16*)(ws + 0);          // 16 MB [8192][1024]
  __hip_bfloat16* wattnT = (__hip_bfloat16*)(ws + 16777216);   //  6 MB [3072][1024]
  __hip_bfloat16* wprojT = (__hip_bfloat16*)(ws + 23068672);   //  2 MB [1024][1024]
  __hip_bfloat16* q_s    = (__hip_bfloat16*)(ws + 25165824);   // 16 MB [64bh][2048][64]
  __hip_bfloat16* k_s    = (__hip_bfloat16*)(ws + 41943040);   // 16 MB [64bh][2048][64]
  __hip_bfloat16* vT_s   = (__hip_bfloat16*)(ws + 58720256);   // 16 MB [64bh][64][2048]
  __hip_bfloat16* y_s    = xb;                                  // reuse xb after gemm1

  prep_all<<<6144, 256, 0, stream>>>(x, xb, w_attn, wattnT, w_proj, wprojT);

  gemm_bf16<0><<<1536, 256, 0, stream>>>(
      xb, wattnT, b_attn, 8192, 3072, 1024, q_s, k_s, vT_s, (float*)nullptr);

  flash_attn<<<2048, 128, 0, stream>>>(q_s, k_s, vT_s, y_s);

  gemm_bf16<1><<<512, 256, 0, stream>>>(
      y_s, wprojT, b_proj, 8192, 1024, 1024,
      (__hip_bfloat16*)nullptr, (__hip_bfloat16*)nullptr, (__hip_bfloat16*)nullptr, out);
}